// Round 15
// baseline (137.979 us; speedup 1.0000x reference)
//
#include <hip/hip_runtime.h>
#include <cstdint>
#include <cstddef>

#define S 8192
#define Dm 1024
#define E 64
#define CAP 128
#define SEC 67108864ull   // S*E*CAP
// out layout (float32 elements), out_size = 1 + 2*SEC + 64 = 134,217,793:
//   [0] l_aux | [1,1+SEC) combine | [1+SEC,1+2SEC) dispatch | [1+2SEC,+64) counts
// K1 fill zeroes elements [0,134217792); leftover element = counts[63] is
// written unconditionally by k_scan.

#define GEMM_BLOCKS 256   // 32 tokens x 64 experts each
#define FILL_BLOCKS 1792  // grid 2048
#define N4ALL 33554448u

typedef float f32x4 __attribute__((ext_vector_type(4)));

// ---------------- K1: fused {GEMM+softmax+argmax} + 537MB zero-fill ----------
// R14 champion, ONE change: DOUBLE-BUFFERED LDS (one barrier per chunk, 16 vs
// 32; ds_writes overlap the previous chunk's compute). Theory: the GEMM's
// ~2x excess over its LDS floor is the per-chunk serialization
// (drain -> barrier -> write phase -> barrier -> refill) with 1 block/CU and
// nothing to fill the bubble. 2-deep p/q register prefetch retained.
__global__ __launch_bounds__(256) void k_main(const float* __restrict__ x,
                                              const float* __restrict__ w,
                                              float* __restrict__ gate,
                                              int* __restrict__ idx,
                                              float* __restrict__ me_part,
                                              float* __restrict__ out) {
    int bid = blockIdx.x;
    int tid = threadIdx.x;
    if (bid < GEMM_BLOCKS) {
        __shared__ float Al[2][32][68];   // 2 x 8.7 KB
        __shared__ float Wl[2][64][68];   // 2 x 17.4 KB   (total 52.2 KB)
        __shared__ float sm[32];
        __shared__ float sinv[32];
        int rt = (tid & 15) * 2;       // token pair base
        int ce = (tid >> 4) * 4;       // expert quad base
        int t0 = bid * 32;
        const float* asrc = x + (size_t)(t0 + (tid >> 3)) * Dm + (tid & 7) * 8;
        const float* wsrc0 = w + (size_t)(tid >> 3) * Dm + (tid & 7) * 8;
        const float* wsrc1 = wsrc0 + 32 * (size_t)Dm;
        int sr = tid >> 3;             // staging row
        int sc = (tid & 7) * 8;        // staging col

        float4 acc0 = make_float4(0.f, 0.f, 0.f, 0.f);  // tok rt,   exp ce..+3
        float4 acc1 = make_float4(0.f, 0.f, 0.f, 0.f);  // tok rt+1, exp ce..+3

        // p = data for even-destined chunks, q = odd (2-deep in flight)
        float4 pa0 = *(const float4*)(asrc + 0);
        float4 pa1 = *(const float4*)(asrc + 4);
        float4 pw0 = *(const float4*)(wsrc0 + 0);
        float4 pw1 = *(const float4*)(wsrc0 + 4);
        float4 pw2 = *(const float4*)(wsrc1 + 0);
        float4 pw3 = *(const float4*)(wsrc1 + 4);
        float4 qa0 = *(const float4*)(asrc + 64);
        float4 qa1 = *(const float4*)(asrc + 68);
        float4 qw0 = *(const float4*)(wsrc0 + 64);
        float4 qw1 = *(const float4*)(wsrc0 + 68);
        float4 qw2 = *(const float4*)(wsrc1 + 64);
        float4 qw3 = *(const float4*)(wsrc1 + 68);

#define WRITE_LDS(B, A0, A1, W0, W1, W2, W3)                                   \
        *(float4*)&Al[B][sr][sc] = A0;                                         \
        *(float4*)&Al[B][sr][sc + 4] = A1;                                     \
        *(float4*)&Wl[B][sr][sc] = W0;                                         \
        *(float4*)&Wl[B][sr][sc + 4] = W1;                                     \
        *(float4*)&Wl[B][32 + sr][sc] = W2;                                    \
        *(float4*)&Wl[B][32 + sr][sc + 4] = W3;

#define LOADP(KB)                                                              \
        pa0 = *(const float4*)(asrc + (KB));                                   \
        pa1 = *(const float4*)(asrc + (KB) + 4);                               \
        pw0 = *(const float4*)(wsrc0 + (KB));                                  \
        pw1 = *(const float4*)(wsrc0 + (KB) + 4);                              \
        pw2 = *(const float4*)(wsrc1 + (KB));                                  \
        pw3 = *(const float4*)(wsrc1 + (KB) + 4);

#define LOADQ(KB)                                                              \
        qa0 = *(const float4*)(asrc + (KB));                                   \
        qa1 = *(const float4*)(asrc + (KB) + 4);                               \
        qw0 = *(const float4*)(wsrc0 + (KB));                                  \
        qw1 = *(const float4*)(wsrc0 + (KB) + 4);                              \
        qw2 = *(const float4*)(wsrc1 + (KB));                                  \
        qw3 = *(const float4*)(wsrc1 + (KB) + 4);

#define INNER_COMPUTE(B)                                                       \
        _Pragma("unroll 4")                                                    \
        for (int k4 = 0; k4 < 16; ++k4) {                                      \
            float4 a0 = *(const float4*)&Al[B][rt][k4 * 4];                    \
            float4 a1 = *(const float4*)&Al[B][rt + 1][k4 * 4];                \
            float4 w0 = *(const float4*)&Wl[B][ce + 0][k4 * 4];                \
            float4 w1 = *(const float4*)&Wl[B][ce + 1][k4 * 4];                \
            float4 w2 = *(const float4*)&Wl[B][ce + 2][k4 * 4];                \
            float4 w3 = *(const float4*)&Wl[B][ce + 3][k4 * 4];                \
            acc0.x = fmaf(a0.w, w0.w, fmaf(a0.z, w0.z, fmaf(a0.y, w0.y, fmaf(a0.x, w0.x, acc0.x)))); \
            acc0.y = fmaf(a0.w, w1.w, fmaf(a0.z, w1.z, fmaf(a0.y, w1.y, fmaf(a0.x, w1.x, acc0.y)))); \
            acc0.z = fmaf(a0.w, w2.w, fmaf(a0.z, w2.z, fmaf(a0.y, w2.y, fmaf(a0.x, w2.x, acc0.z)))); \
            acc0.w = fmaf(a0.w, w3.w, fmaf(a0.z, w3.z, fmaf(a0.y, w3.y, fmaf(a0.x, w3.x, acc0.w)))); \
            acc1.x = fmaf(a1.w, w0.w, fmaf(a1.z, w0.z, fmaf(a1.y, w0.y, fmaf(a1.x, w0.x, acc1.x)))); \
            acc1.y = fmaf(a1.w, w1.w, fmaf(a1.z, w1.z, fmaf(a1.y, w1.y, fmaf(a1.x, w1.x, acc1.y)))); \
            acc1.z = fmaf(a1.w, w2.w, fmaf(a1.z, w2.z, fmaf(a1.y, w2.y, fmaf(a1.x, w2.x, acc1.z)))); \
            acc1.w = fmaf(a1.w, w3.w, fmaf(a1.z, w3.z, fmaf(a1.y, w3.y, fmaf(a1.x, w3.x, acc1.w)))); \
        }

        // prologue: buf0 <- ch0(p); p <- ch2
        WRITE_LDS(0, pa0, pa1, pw0, pw1, pw2, pw3)
        LOADP(2 * 64)
        __syncthreads();

        for (int ch = 0; ch < 16; ch += 2) {
            // even chunk ch: compute buf0; meanwhile buf1 <- q (ch+1); q <- ch+3
            WRITE_LDS(1, qa0, qa1, qw0, qw1, qw2, qw3)
            if (ch + 3 < 16) { LOADQ((ch + 3) * 64) }
            INNER_COMPUTE(0)
            __syncthreads();
            // odd chunk ch+1: compute buf1; meanwhile buf0 <- p (ch+2); p <- ch+4
            if (ch + 2 < 16) { WRITE_LDS(0, pa0, pa1, pw0, pw1, pw2, pw3) }
            if (ch + 4 < 16) { LOADP((ch + 4) * 64) }
            INNER_COMPUTE(1)
            __syncthreads();
        }
#undef WRITE_LDS
#undef LOADP
#undef LOADQ
#undef INNER_COMPUTE
        // ---- epilogue: logits tile -> LDS (reuse Al[0]), softmax/argmax ----
        Al[0][rt][ce + 0] = acc0.x; Al[0][rt][ce + 1] = acc0.y;
        Al[0][rt][ce + 2] = acc0.z; Al[0][rt][ce + 3] = acc0.w;
        Al[0][rt + 1][ce + 0] = acc1.x; Al[0][rt + 1][ce + 1] = acc1.y;
        Al[0][rt + 1][ce + 2] = acc1.z; Al[0][rt + 1][ce + 3] = acc1.w;
        __syncthreads();
        if (tid < 32) {   // row phase: first-index argmax + exp-sum
            float m = Al[0][tid][0];
            int am = 0;
#pragma unroll
            for (int c = 1; c < E; ++c) {
                float v = Al[0][tid][c];
                if (v > m) { m = v; am = c; }
            }
            float ssum = 0.f;
#pragma unroll
            for (int c = 0; c < E; ++c) ssum += __expf(Al[0][tid][c] - m);
            float inv = 1.0f / ssum;   // softmax value at the argmax
            gate[t0 + tid] = inv;
            idx[t0 + tid] = am;
            sm[tid] = m;
            sinv[tid] = inv;
        }
        __syncthreads();
        if (tid < E) {    // column phase: partial me sums (deterministic)
            float cs = 0.f;
#pragma unroll 8
            for (int r = 0; r < 32; ++r)
                cs += __expf(Al[0][r][tid] - sm[r]) * sinv[r];
            me_part[bid * E + tid] = cs;
        }
    } else {
        int fb = bid - GEMM_BLOCKS;
        f32x4 z = {0.f, 0.f, 0.f, 0.f};
        f32x4* o4 = (f32x4*)out;
        for (unsigned i = (unsigned)fb * 256u + tid; i < N4ALL;
             i += FILL_BLOCKS * 256u)
            o4[i] = z;
    }
}

// ---------------- K2: ordered scan + scatter + counts + me-reduce + l_aux ----
// R8's proven kernel, verbatim. 64 blocks (one per expert) x 256 threads.
__global__ __launch_bounds__(256) void k_scan(const int* __restrict__ idx,
                                              const float* __restrict__ gate,
                                              const float* __restrict__ me_part,
                                              float* __restrict__ out) {
    int e = blockIdx.x;
    int tid = threadIdx.x;
    int lane = tid & 63;
    int wid = tid >> 6;
    __shared__ int wsum[4];
    __shared__ float red[256];
    int running = 0;
    for (int ch = 0; ch < S / 256; ++ch) {
        int t = ch * 256 + tid;
        bool f = (idx[t] == e);
        unsigned long long b = __ballot(f);
        int pre = __popcll(b & ((1ull << lane) - 1ull));
        if (lane == 0) wsum[wid] = __popcll(b);
        __syncthreads();
        int off = running;
#pragma unroll
        for (int w2 = 0; w2 < 4; ++w2)
            if (w2 < wid) off += wsum[w2];
        int p = off + pre;
        if (f && p < CAP) {
            size_t o = 1 + (size_t)t * (E * CAP) + (size_t)e * CAP + (size_t)p;
            out[o] = gate[t];                 // combine_weights
            out[o + (size_t)SEC] = 1.0f;      // dispatch_mask
        }
        running += wsum[0] + wsum[1] + wsum[2] + wsum[3];
        __syncthreads();
    }
    // me reduction: me_sum[e] = sum over 256 GEMM blocks' partials
    red[tid] = me_part[tid * E + e];
    __syncthreads();
    for (int s2 = 128; s2 > 0; s2 >>= 1) {
        if (tid < s2) red[tid] += red[tid + s2];
        __syncthreads();
    }
    if (tid == 0) {
        out[1 + 2 * (size_t)SEC + e] = (float)running;   // exp_counts (pre-drop)
        float la = red[0] * (1.0f / (float)S) *
                   ((float)running / (float)S) * (float)E;
        atomicAdd(out, la);                              // l_aux
    }
}

extern "C" void kernel_launch(void* const* d_in, const int* in_sizes, int n_in,
                              void* d_out, int out_size, void* d_ws, size_t ws_size,
                              hipStream_t stream) {
    const float* x = (const float*)d_in[0];      // [S, Dm] fp32
    const float* w = (const float*)d_in[1];      // [E, Dm] fp32
    float* out = (float*)d_out;

    // ws layout
    float* me_part = (float*)d_ws;               // [256][64] = 64 KB
    float* gate = me_part + GEMM_BLOCKS * E;     // S floats
    int* idx = (int*)(gate + S);                 // S ints

    k_main<<<dim3(GEMM_BLOCKS + FILL_BLOCKS), dim3(256), 0, stream>>>(
        x, w, gate, idx, me_part, out);
    k_scan<<<dim3(64), dim3(256), 0, stream>>>(idx, gate, me_part, out);
}

// Round 16
// 136.655 us; speedup vs baseline: 1.0097x; 1.0097x over previous
//
#include <hip/hip_runtime.h>
#include <cstdint>
#include <cstddef>

#define S 8192
#define Dm 1024
#define E 64
#define CAP 128
#define SEC 67108864ull   // S*E*CAP
// out layout (float32 elements), out_size = 1 + 2*SEC + 64 = 134,217,793:
//   [0] l_aux | [1,1+SEC) combine | [1+SEC,1+2SEC) dispatch | [1+2SEC,+64) counts
// K1 fill zeroes elements [0,134217792); leftover element = counts[63] is
// written unconditionally by k_scan.

#define GEMM_BLOCKS 256   // 32 tokens x 64 experts each
#define FILL_BLOCKS 1792  // grid 2048
#define N4ALL 33554448u
#define WSCALE 4096.0f    // keep w_hi/w_lo out of fp16-denorm range
#define INV_WSCALE (1.0f / 4096.0f)

typedef float f32x4 __attribute__((ext_vector_type(4)));
typedef _Float16 f16x8 __attribute__((ext_vector_type(8)));
typedef float f32x4b __attribute__((ext_vector_type(4)));

// convert 8 fp32 (two float4) -> f16 hi + f16 lo, store as 16B each
#define CV8(H, L, ROW, COL, V0, V1, SCALE) do {                                \
    f16x8 hh, ll; float t_;                                                    \
    t_ = (V0).x * (SCALE); hh[0] = (_Float16)t_; ll[0] = (_Float16)(t_ - (float)hh[0]); \
    t_ = (V0).y * (SCALE); hh[1] = (_Float16)t_; ll[1] = (_Float16)(t_ - (float)hh[1]); \
    t_ = (V0).z * (SCALE); hh[2] = (_Float16)t_; ll[2] = (_Float16)(t_ - (float)hh[2]); \
    t_ = (V0).w * (SCALE); hh[3] = (_Float16)t_; ll[3] = (_Float16)(t_ - (float)hh[3]); \
    t_ = (V1).x * (SCALE); hh[4] = (_Float16)t_; ll[4] = (_Float16)(t_ - (float)hh[4]); \
    t_ = (V1).y * (SCALE); hh[5] = (_Float16)t_; ll[5] = (_Float16)(t_ - (float)hh[5]); \
    t_ = (V1).z * (SCALE); hh[6] = (_Float16)t_; ll[6] = (_Float16)(t_ - (float)hh[6]); \
    t_ = (V1).w * (SCALE); hh[7] = (_Float16)t_; ll[7] = (_Float16)(t_ - (float)hh[7]); \
    *(f16x8*)&H[ROW][COL] = hh;                                                \
    *(f16x8*)&L[ROW][COL] = ll;                                                \
} while (0)

// ---------------- K1: fused {MFMA-GEMM+softmax+argmax} + 537MB zero-fill -----
// R14 champion, ONE change: the GEMM math runs on matrix cores via the
// fp16x3 trick (x·w = hi·hi + lo·hi + hi·lo; fp32-equivalent logits, error
// ~1e-6 << min argmax gap). Staging converts fp32->f16 hi/lo at LDS-write
// time; 2-deep p/q register prefetch and the fill branch are unchanged.
// Discriminates the two stall models: if GEMM critical path was the wall,
// k_main drops to ~max(fill, staging) ~ 95-105us; if mixed-BW roofline, ~null.
__global__ __launch_bounds__(256) void k_main(const float* __restrict__ x,
                                              const float* __restrict__ w,
                                              float* __restrict__ gate,
                                              int* __restrict__ idx,
                                              float* __restrict__ me_part,
                                              float* __restrict__ out) {
    int bid = blockIdx.x;
    int tid = threadIdx.x;
    if (bid < GEMM_BLOCKS) {
        __shared__ _Float16 Ah[32][80];   // 5 KB   (row 160B: b128-aligned)
        __shared__ _Float16 Alo[32][80];  // 5 KB
        __shared__ _Float16 Wh[64][80];   // 10 KB
        __shared__ _Float16 Wlo[64][80];  // 10 KB
        __shared__ float Sl[32][66];      // 8.4 KB logits tile (epilogue)
        __shared__ float sm[32];
        __shared__ float sinv[32];
        int t0 = bid * 32;
        int sr = tid >> 3;             // staging row 0..31
        int sc = (tid & 7) * 8;        // staging col (halves/floats)
        const float* asrc = x + (size_t)(t0 + sr) * Dm + (tid & 7) * 8;
        const float* wsrc0 = w + (size_t)sr * Dm + (tid & 7) * 8;
        const float* wsrc1 = wsrc0 + 32 * (size_t)Dm;

        // MFMA work split: wave wv -> m-tile (wv&1), n-pair (wv>>1)
        int wv = tid >> 6;
        int l = tid & 63;
        int lr = l & 15;               // A row / B col within tile
        int lg = l >> 4;               // k-group 0..3
        int mt = wv & 1;               // m-tile 0/1 (16 tokens each)
        int np = wv >> 1;              // n-pair 0/1 (32 experts each)
        f32x4b acc0 = {0.f, 0.f, 0.f, 0.f};   // n-tile np*2
        f32x4b acc1 = {0.f, 0.f, 0.f, 0.f};   // n-tile np*2+1

        // 2-deep prefetch: p = even chunks, q = odd chunks
        float4 pa0 = *(const float4*)(asrc + 0);
        float4 pa1 = *(const float4*)(asrc + 4);
        float4 pw0 = *(const float4*)(wsrc0 + 0);
        float4 pw1 = *(const float4*)(wsrc0 + 4);
        float4 pw2 = *(const float4*)(wsrc1 + 0);
        float4 pw3 = *(const float4*)(wsrc1 + 4);
        float4 qa0 = *(const float4*)(asrc + 64);
        float4 qa1 = *(const float4*)(asrc + 68);
        float4 qw0 = *(const float4*)(wsrc0 + 64);
        float4 qw1 = *(const float4*)(wsrc0 + 68);
        float4 qw2 = *(const float4*)(wsrc1 + 64);
        float4 qw3 = *(const float4*)(wsrc1 + 68);

#define WRITE_LDS(A0, A1, W0, W1, W2, W3)                                      \
        CV8(Ah, Alo, sr, sc, A0, A1, 1.0f);                                    \
        CV8(Wh, Wlo, sr, sc, W0, W1, WSCALE);                                  \
        CV8(Wh, Wlo, (32 + sr), sc, W2, W3, WSCALE);

#define LOADP(KB)                                                              \
        pa0 = *(const float4*)(asrc + (KB));                                   \
        pa1 = *(const float4*)(asrc + (KB) + 4);                               \
        pw0 = *(const float4*)(wsrc0 + (KB));                                  \
        pw1 = *(const float4*)(wsrc0 + (KB) + 4);                              \
        pw2 = *(const float4*)(wsrc1 + (KB));                                  \
        pw3 = *(const float4*)(wsrc1 + (KB) + 4);

#define LOADQ(KB)                                                              \
        qa0 = *(const float4*)(asrc + (KB));                                   \
        qa1 = *(const float4*)(asrc + (KB) + 4);                               \
        qw0 = *(const float4*)(wsrc0 + (KB));                                  \
        qw1 = *(const float4*)(wsrc0 + (KB) + 4);                              \
        qw2 = *(const float4*)(wsrc1 + (KB));                                  \
        qw3 = *(const float4*)(wsrc1 + (KB) + 4);

#define INNER_MFMA                                                             \
        _Pragma("unroll")                                                      \
        for (int ks = 0; ks < 2; ++ks) {                                       \
            int kc = ks * 32 + lg * 8;                                         \
            f16x8 ah = *(const f16x8*)&Ah[mt * 16 + lr][kc];                   \
            f16x8 al = *(const f16x8*)&Alo[mt * 16 + lr][kc];                  \
            f16x8 bh0 = *(const f16x8*)&Wh[np * 32 + lr][kc];                  \
            f16x8 bl0 = *(const f16x8*)&Wlo[np * 32 + lr][kc];                 \
            f16x8 bh1 = *(const f16x8*)&Wh[np * 32 + 16 + lr][kc];             \
            f16x8 bl1 = *(const f16x8*)&Wlo[np * 32 + 16 + lr][kc];            \
            acc0 = __builtin_amdgcn_mfma_f32_16x16x32_f16(ah, bh0, acc0, 0, 0, 0); \
            acc0 = __builtin_amdgcn_mfma_f32_16x16x32_f16(al, bh0, acc0, 0, 0, 0); \
            acc0 = __builtin_amdgcn_mfma_f32_16x16x32_f16(ah, bl0, acc0, 0, 0, 0); \
            acc1 = __builtin_amdgcn_mfma_f32_16x16x32_f16(ah, bh1, acc1, 0, 0, 0); \
            acc1 = __builtin_amdgcn_mfma_f32_16x16x32_f16(al, bh1, acc1, 0, 0, 0); \
            acc1 = __builtin_amdgcn_mfma_f32_16x16x32_f16(ah, bl1, acc1, 0, 0, 0); \
        }

        for (int ch = 0; ch < 16; ch += 2) {
            // even chunk: write p -> LDS, refill p (ch+2), compute
            __syncthreads();
            WRITE_LDS(pa0, pa1, pw0, pw1, pw2, pw3)
            __syncthreads();
            if (ch + 2 < 16) { LOADP((ch + 2) * 64) }
            INNER_MFMA
            // odd chunk: write q -> LDS, refill q (ch+3), compute
            __syncthreads();
            WRITE_LDS(qa0, qa1, qw0, qw1, qw2, qw3)
            __syncthreads();
            if (ch + 3 < 16) { LOADQ((ch + 3) * 64) }
            INNER_MFMA
        }
#undef WRITE_LDS
#undef LOADP
#undef LOADQ
#undef INNER_MFMA
        __syncthreads();
        // ---- D -> Sl (m89-verified C/D layout: row=(l>>4)*4+r, col=l&15) ----
#pragma unroll
        for (int r = 0; r < 4; ++r) {
            Sl[mt * 16 + lg * 4 + r][np * 32 + lr] = acc0[r] * INV_WSCALE;
            Sl[mt * 16 + lg * 4 + r][np * 32 + 16 + lr] = acc1[r] * INV_WSCALE;
        }
        __syncthreads();
        if (tid < 32) {   // row phase: first-index argmax + exp-sum
            float m = Sl[tid][0];
            int am = 0;
#pragma unroll
            for (int c = 1; c < E; ++c) {
                float v = Sl[tid][c];
                if (v > m) { m = v; am = c; }
            }
            float ssum = 0.f;
#pragma unroll
            for (int c = 0; c < E; ++c) ssum += __expf(Sl[tid][c] - m);
            float inv = 1.0f / ssum;   // softmax value at the argmax
            gate[t0 + tid] = inv;
            idx[t0 + tid] = am;
            sm[tid] = m;
            sinv[tid] = inv;
        }
        __syncthreads();
        if (tid < E) {    // column phase: partial me sums (deterministic)
            float cs = 0.f;
#pragma unroll 8
            for (int r = 0; r < 32; ++r)
                cs += __expf(Sl[r][tid] - sm[r]) * sinv[r];
            me_part[bid * E + tid] = cs;
        }
    } else {
        int fb = bid - GEMM_BLOCKS;
        f32x4 z = {0.f, 0.f, 0.f, 0.f};
        f32x4* o4 = (f32x4*)out;
        for (unsigned i = (unsigned)fb * 256u + tid; i < N4ALL;
             i += FILL_BLOCKS * 256u)
            o4[i] = z;
    }
}

// ---------------- K2: ordered scan + scatter + counts + me-reduce + l_aux ----
// R8's proven kernel, verbatim. 64 blocks (one per expert) x 256 threads.
__global__ __launch_bounds__(256) void k_scan(const int* __restrict__ idx,
                                              const float* __restrict__ gate,
                                              const float* __restrict__ me_part,
                                              float* __restrict__ out) {
    int e = blockIdx.x;
    int tid = threadIdx.x;
    int lane = tid & 63;
    int wid = tid >> 6;
    __shared__ int wsum[4];
    __shared__ float red[256];
    int running = 0;
    for (int ch = 0; ch < S / 256; ++ch) {
        int t = ch * 256 + tid;
        bool f = (idx[t] == e);
        unsigned long long b = __ballot(f);
        int pre = __popcll(b & ((1ull << lane) - 1ull));
        if (lane == 0) wsum[wid] = __popcll(b);
        __syncthreads();
        int off = running;
#pragma unroll
        for (int w2 = 0; w2 < 4; ++w2)
            if (w2 < wid) off += wsum[w2];
        int p = off + pre;
        if (f && p < CAP) {
            size_t o = 1 + (size_t)t * (E * CAP) + (size_t)e * CAP + (size_t)p;
            out[o] = gate[t];                 // combine_weights
            out[o + (size_t)SEC] = 1.0f;      // dispatch_mask
        }
        running += wsum[0] + wsum[1] + wsum[2] + wsum[3];
        __syncthreads();
    }
    // me reduction: me_sum[e] = sum over 256 GEMM blocks' partials
    red[tid] = me_part[tid * E + e];
    __syncthreads();
    for (int s2 = 128; s2 > 0; s2 >>= 1) {
        if (tid < s2) red[tid] += red[tid + s2];
        __syncthreads();
    }
    if (tid == 0) {
        out[1 + 2 * (size_t)SEC + e] = (float)running;   // exp_counts (pre-drop)
        float la = red[0] * (1.0f / (float)S) *
                   ((float)running / (float)S) * (float)E;
        atomicAdd(out, la);                              // l_aux
    }
}

extern "C" void kernel_launch(void* const* d_in, const int* in_sizes, int n_in,
                              void* d_out, int out_size, void* d_ws, size_t ws_size,
                              hipStream_t stream) {
    const float* x = (const float*)d_in[0];      // [S, Dm] fp32
    const float* w = (const float*)d_in[1];      // [E, Dm] fp32
    float* out = (float*)d_out;

    // ws layout
    float* me_part = (float*)d_ws;               // [256][64] = 64 KB
    float* gate = me_part + GEMM_BLOCKS * E;     // S floats
    int* idx = (int*)(gate + S);                 // S ints

    k_main<<<dim3(GEMM_BLOCKS + FILL_BLOCKS), dim3(256), 0, stream>>>(
        x, w, gate, idx, me_part, out);
    k_scan<<<dim3(64), dim3(256), 0, stream>>>(idx, gate, me_part, out);
}